// Round 8
// baseline (191603.015 us; speedup 1.0000x reference)
//
#include <hip/hip_runtime.h>
#include <hip/hip_bf16.h>

#define NMEL 80

typedef unsigned u32x4 __attribute__((ext_vector_type(4)));

__device__ __forceinline__ float bf2f(unsigned short u) {
  unsigned v = ((unsigned)u) << 16; float f; __builtin_memcpy(&f, &v, 4); return f;
}
__device__ __forceinline__ unsigned short f2bf_u(float f) {
  __hip_bfloat16 h = __float2bfloat16(f); unsigned short u; __builtin_memcpy(&u, &h, 2); return u;
}
__device__ __forceinline__ void unpk(unsigned u, float& lo, float& hi) {
  unsigned l = u << 16, h = u & 0xffff0000u;
  __builtin_memcpy(&lo, &l, 4); __builtin_memcpy(&hi, &h, 4);
}
__device__ __forceinline__ float agload(const float* p) {
  return __hip_atomic_load(p, __ATOMIC_RELAXED, __HIP_MEMORY_SCOPE_AGENT);
}
__device__ __forceinline__ void agstore(float* p, float v) {
  __hip_atomic_store(p, v, __ATOMIC_RELAXED, __HIP_MEMORY_SCOPE_AGENT);
}

// ---------------- workspace layout (bytes) ----------------
constexpr size_t OFF_ATTNT = 0;                                  // bf16 [65536 rows][256 a] (u32 pairs)
constexpr size_t SZ_ATTNT = (size_t)65536 * 256 * 2;             // 33,554,432
constexpr size_t OFF_PRE2 = OFF_ATTNT + SZ_ATTNT;                // bf16 [64000][256]
constexpr size_t SZ_PRE2 = (size_t)64000 * 256 * 2;
constexpr size_t OFF_WDT = OFF_PRE2 + SZ_PRE2;                   // f32 float4[kq][256]
constexpr size_t SZ_WDT = (size_t)65536 * 4;
constexpr size_t OFF_WHT = OFF_WDT + SZ_WDT;                     // f32 float4[kq][1024]
constexpr size_t SZ_W1M = (size_t)262144 * 4;
constexpr size_t OFF_WCT = OFF_WHT + SZ_W1M;
constexpr size_t OFF_WPT = OFF_WCT + SZ_W1M;
constexpr size_t OFF_BIASG = OFF_WPT + SZ_W1M;                   // f32 [1024]
constexpr size_t SZ_BIASG = 1024 * 4;
constexpr size_t OFF_EXCH = (OFF_BIASG + SZ_BIASG + 255) & ~(size_t)255;
constexpr size_t EXF_CTX = 0;                        // [512][256] f32 ctx partials
constexpr size_t EXF_S = EXF_CTX + (size_t)512 * 256;  // [512] softmax partial sums
constexpr size_t EXF_G = EXF_S + 512;                // [512][128] gate slices
constexpr size_t EXF_CTR = EXF_G + (size_t)512 * 128;  // u32 [64] barrier counters
constexpr size_t EXCH_FLOATS = EXF_CTR + 64;
constexpr size_t WS_NEED = OFF_EXCH + EXCH_FLOATS * 4;   // ~71 MiB

// ---------------- weight re-layout (fp32, row-coalesced float4) ----------------
__global__ __launch_bounds__(256) void prep_w2(
    const float* __restrict__ W_dec, const float* __restrict__ W_hh,
    const float* __restrict__ W_ih, const float* __restrict__ b_ih,
    const float* __restrict__ b_hh,
    float* __restrict__ WdT, float* __restrict__ WhT,
    float* __restrict__ WcT, float* __restrict__ WpT, float* __restrict__ biasG) {
  int idx = blockIdx.x * 256 + threadIdx.x;
  if (idx < 65536) {                       // WdT[kq][a][q] = W_dec[a][4kq+q]
    int q = idx & 3, a = (idx >> 2) & 255, kq = idx >> 10;
    WdT[idx] = W_dec[(size_t)a * 256 + kq * 4 + q];
  } else if (idx < 327680) {               // WhT[kq][g][q] = W_hh[g][4kq+q]
    int i = idx - 65536;
    int q = i & 3, g = (i >> 2) & 1023, kq = i >> 12;
    WhT[i] = W_hh[(size_t)g * 256 + kq * 4 + q];
  } else if (idx < 589824) {               // WcT: ctx part of W_ih (cols 256..511)
    int i = idx - 327680;
    int q = i & 3, g = (i >> 2) & 1023, kq = i >> 12;
    WcT[i] = W_ih[(size_t)g * 512 + 256 + kq * 4 + q];
  } else if (idx < 851968) {               // WpT: prenet part of W_ih (cols 0..255)
    int i = idx - 589824;
    int q = i & 3, g = (i >> 2) & 1023, kq = i >> 12;
    WpT[i] = W_ih[(size_t)g * 512 + kq * 4 + q];
  } else if (idx < 852992) {
    int g = idx - 851968;
    biasG[g] = b_ih[g] + b_hh[g];
  }
}

// ---------------- attn_enc GEMM -> row-major bf16 attnT (scaled by 2*log2e) ----------------
__global__ __launch_bounds__(256) void attn_gemm(const float* __restrict__ enc,
                                                 const float* __restrict__ W_enc,
                                                 const float* __restrict__ b_enc,
                                                 unsigned* __restrict__ attnT) {
  __shared__ unsigned short Alds[64 * 260];
  const int tid = threadIdx.x;
  const int row0 = blockIdx.x * 64;
  const int wv = tid >> 6, lane = tid & 63, nb = wv * 64;
  for (int idx = tid; idx < 64 * 256; idx += 256) {
    int r = idx >> 8, k = idx & 255;
    Alds[r * 260 + k] = f2bf_u(enc[(size_t)(row0 + r) * 256 + k]);
  }
  __syncthreads();
  float acc[64];
#pragma unroll
  for (int n = 0; n < 64; ++n) acc[n] = b_enc[nb + n];
  for (int k8 = 0; k8 < 256; k8 += 8) {
    ushort4 ua = *(const ushort4*)&Alds[lane * 260 + k8];
    ushort4 ub = *(const ushort4*)&Alds[lane * 260 + k8 + 4];
    float a0 = bf2f(ua.x), a1 = bf2f(ua.y), a2 = bf2f(ua.z), a3 = bf2f(ua.w);
    float a4 = bf2f(ub.x), a5 = bf2f(ub.y), a6 = bf2f(ub.z), a7 = bf2f(ub.w);
#pragma unroll
    for (int n = 0; n < 64; ++n) {
      const float4* wp = (const float4*)(W_enc + (size_t)(nb + n) * 256 + k8);
      float4 w0 = wp[0], w1 = wp[1];
      acc[n] = fmaf(a0, w0.x, acc[n]); acc[n] = fmaf(a1, w0.y, acc[n]);
      acc[n] = fmaf(a2, w0.z, acc[n]); acc[n] = fmaf(a3, w0.w, acc[n]);
      acc[n] = fmaf(a4, w1.x, acc[n]); acc[n] = fmaf(a5, w1.y, acc[n]);
      acc[n] = fmaf(a6, w1.z, acc[n]); acc[n] = fmaf(a7, w1.w, acc[n]);
    }
  }
  const float CE = 2.8853900817779268f;  // 2*log2(e)
  unsigned* rowp = attnT + (size_t)(row0 + lane) * 128 + (nb >> 1);
#pragma unroll
  for (int n = 0; n < 64; n += 2)
    rowp[n >> 1] = (unsigned)f2bf_u(acc[n] * CE) | ((unsigned)f2bf_u(acc[n + 1] * CE) << 16);
}

// ---------------- fused prenet (unchanged) ----------------
__global__ __launch_bounds__(256) void prenet_fused(const float* __restrict__ tmel,
                                                    const float* __restrict__ W1,
                                                    const float* __restrict__ b1,
                                                    const float* __restrict__ W2,
                                                    const float* __restrict__ b2,
                                                    unsigned short* __restrict__ pre2) {
  __shared__ unsigned short Alds[64 * 260];
  const int tid = threadIdx.x;
  const int row0 = blockIdx.x * 64;
  const int wv = tid >> 6, lane = tid & 63, nb = wv * 64;
  for (int idx = tid; idx < 64 * 80; idx += 256) {
    int r = idx / 80, k = idx - r * 80;
    int R = row0 + r;
    float v = (R % 1000 != 0) ? tmel[(size_t)(R - 1) * NMEL + k] : 0.f;
    Alds[r * 260 + k] = f2bf_u(v);
  }
  __syncthreads();
  float acc[64];
#pragma unroll
  for (int n = 0; n < 64; ++n) acc[n] = b1[nb + n];
  for (int k8 = 0; k8 < 80; k8 += 8) {
    ushort4 ua = *(const ushort4*)&Alds[lane * 260 + k8];
    ushort4 ub = *(const ushort4*)&Alds[lane * 260 + k8 + 4];
    float a0 = bf2f(ua.x), a1 = bf2f(ua.y), a2 = bf2f(ua.z), a3 = bf2f(ua.w);
    float a4 = bf2f(ub.x), a5 = bf2f(ub.y), a6 = bf2f(ub.z), a7 = bf2f(ub.w);
#pragma unroll
    for (int n = 0; n < 64; ++n) {
      const float4* wp = (const float4*)(W1 + (size_t)(nb + n) * 80 + k8);
      float4 w0 = wp[0], w1 = wp[1];
      acc[n] = fmaf(a0, w0.x, acc[n]); acc[n] = fmaf(a1, w0.y, acc[n]);
      acc[n] = fmaf(a2, w0.z, acc[n]); acc[n] = fmaf(a3, w0.w, acc[n]);
      acc[n] = fmaf(a4, w1.x, acc[n]); acc[n] = fmaf(a5, w1.y, acc[n]);
      acc[n] = fmaf(a6, w1.z, acc[n]); acc[n] = fmaf(a7, w1.w, acc[n]);
    }
  }
  __syncthreads();
#pragma unroll
  for (int n = 0; n < 64; ++n) Alds[lane * 260 + nb + n] = f2bf_u(fmaxf(acc[n], 0.f));
  __syncthreads();
#pragma unroll
  for (int n = 0; n < 64; ++n) acc[n] = b2[nb + n];
  for (int k8 = 0; k8 < 256; k8 += 8) {
    ushort4 ua = *(const ushort4*)&Alds[lane * 260 + k8];
    ushort4 ub = *(const ushort4*)&Alds[lane * 260 + k8 + 4];
    float a0 = bf2f(ua.x), a1 = bf2f(ua.y), a2 = bf2f(ua.z), a3 = bf2f(ua.w);
    float a4 = bf2f(ub.x), a5 = bf2f(ub.y), a6 = bf2f(ub.z), a7 = bf2f(ub.w);
#pragma unroll
    for (int n = 0; n < 64; ++n) {
      const float4* wp = (const float4*)(W2 + (size_t)(nb + n) * 256 + k8);
      float4 w0 = wp[0], w1 = wp[1];
      acc[n] = fmaf(a0, w0.x, acc[n]); acc[n] = fmaf(a1, w0.y, acc[n]);
      acc[n] = fmaf(a2, w0.z, acc[n]); acc[n] = fmaf(a3, w0.w, acc[n]);
      acc[n] = fmaf(a4, w1.x, acc[n]); acc[n] = fmaf(a5, w1.y, acc[n]);
      acc[n] = fmaf(a6, w1.z, acc[n]); acc[n] = fmaf(a7, w1.w, acc[n]);
    }
  }
  __syncthreads();
#pragma unroll
  for (int n = 0; n < 64; ++n) Alds[lane * 260 + nb + n] = f2bf_u(fmaxf(acc[n], 0.f));
  __syncthreads();
  for (int idx = tid; idx < 64 * 128; idx += 256) {
    int r = idx >> 7, k2 = (idx & 127) * 2;
    unsigned pair = (unsigned)Alds[r * 260 + k2] | ((unsigned)Alds[r * 260 + k2 + 1] << 16);
    *(unsigned*)(pre2 + (size_t)(row0 + r) * 256 + k2) = pair;
  }
}

// ---------------- resident split decoder ----------------
// 512 WGs x 256 threads; WG = (b, s): batch b, te-slice s*128..s*128+128.
// attn slice (64 KB) LDS-resident for all 1000 steps; enc slice in 64 pinned VGPRs.
// LDS ~76 KB -> exactly 2 WGs/CU -> all 512 WGs co-resident (no stranding possible).
// Per-step: zero stream traffic; weights from L2; 2 agent-scope barriers per step
// (8 WGs per batch) with ~1.5 KB exchange. launch_bounds(256,2) caps VGPR at 256.
__global__ __launch_bounds__(256, 2) void decoder_split(
    const unsigned* __restrict__ attnT, const float* __restrict__ enc,
    const unsigned short* __restrict__ pre2,
    const float* __restrict__ WdT, const float4* __restrict__ WhT,
    const float4* __restrict__ WcT, const float4* __restrict__ WpT,
    const float* __restrict__ biasG,
    const float* __restrict__ b_dec, const float* __restrict__ v_w,
    const float* __restrict__ v_b, const float* __restrict__ enc_mask,
    const float* __restrict__ mel_W, const float* __restrict__ mel_b,
    const float* __restrict__ stop_W, const float* __restrict__ stop_b,
    float* exch, unsigned* ctr, float* __restrict__ out) {
  __shared__ __align__(16) unsigned short attn_lds[128 * 260];  // 66,560 B
  __shared__ __align__(16) float dec_lds[256];
  __shared__ __align__(16) float v2_lds[256];
  __shared__ __align__(16) float h_lds[256];
  __shared__ __align__(16) float ctx_lds[256];
  __shared__ __align__(16) float pre_lds[256];
  __shared__ __align__(16) float ctxp_lds[4 * 256];
  __shared__ __align__(16) float scratch[256];
  __shared__ float p_lds[128];
  __shared__ float red_lds[16];

  const int tid = threadIdx.x;
  const int b = blockIdx.x >> 3, s = blockIdx.x & 7;
  const int tloc = tid & 127, chunk = tid >> 7;
  const int lane = tid & 63, w = tid >> 6;   // wave 0..3
  const float CE = 2.8853900817779268f;      // 2*log2(e)
  const float L2E = 1.4426950408889634f;     // log2(e)

  // ---- init ----
  h_lds[tid] = 0.f;
  {
    float v = v_w[tid];
    v2_lds[tid] = -2.f * v;
    for (int m = 32; m; m >>= 1) v += __shfl_xor(v, m);
    if (lane == 0) red_lds[w] = v;
  }
  float c_reg = 0.f;
  const float maskv = (tid < 128) ? enc_mask[b * 1024 + s * 128 + tloc] : 0.f;
  const float bdec_r = b_dec[tid];
  const float biasg_r = biasG[s * 128 + tloc];
  const float melb_r = (tid < 160 && (tid & 1) == 0) ? mel_b[tid >> 1] : 0.f;
  float stopw[8];
  if (w == 3) {
#pragma unroll
    for (int i = 0; i < 8; ++i) stopw[i] = stop_W[lane * 8 + i];
  }
  __syncthreads();
  const float Sv_vb = red_lds[0] + red_lds[1] + red_lds[2] + red_lds[3] + v_b[0];
  const float stopb0 = stop_b[0];

  // ---- stage attn slice into LDS (once) ----
  {
    const unsigned* aT = attnT + ((size_t)(b * 1024 + s * 128)) * 128;
    for (int idx = tid; idx < 128 * 128; idx += 256) {
      int r = idx >> 7, c2 = idx & 127;
      *(unsigned*)&attn_lds[r * 260 + c2 * 2] = aT[(size_t)r * 128 + c2];
    }
  }
  // ---- stage enc slice into registers (once): wave w holds te = s*128+w*32..+32 ----
  uint2 enc_r2[32];
  {
    const float4* eF = (const float4*)enc + ((size_t)(b * 1024 + s * 128 + w * 32)) * 64 + lane;
#pragma unroll
    for (int i = 0; i < 32; ++i) {
      float4 x = eF[(size_t)i << 6];
      enc_r2[i].x = (unsigned)f2bf_u(x.x) | ((unsigned)f2bf_u(x.y) << 16);
      enc_r2[i].y = (unsigned)f2bf_u(x.z) | ((unsigned)f2bf_u(x.w) << 16);
    }
#pragma unroll
    for (int i = 0; i < 32; ++i) { asm volatile("" : "+v"(enc_r2[i].x)); asm volatile("" : "+v"(enc_r2[i].y)); }
  }
  __syncthreads();

  float* ctxP = exch + EXF_CTX;
  float* sP = exch + EXF_S;
  float* gP = exch + EXF_G;
  unsigned* ctrb = ctr + b;
  unsigned epoch = 0;

  const float4* wd = (const float4*)WdT + tid;           // [kq*256 + a], a = tid
  const float4* wpB = WpT + (s * 128 + tloc);            // float4 idx kq*1024 + g
  const float4* wcB = WcT + (s * 128 + tloc);
  const float4* whB = WhT + (s * 128 + tloc);
  const unsigned short* pre2_b = pre2 + (size_t)b * 256000;
  float* outm = out + (size_t)b * 80000;
  float* outs = out + (size_t)5120000 + b * 1000;

  for (int it = 0; it < 1000; ++it) {
    // ---- P1: pre load + full dec (thread = row a = tid) ----
    {
      pre_lds[tid] = bf2f(pre2_b[it * 256 + tid]);
      float acc = bdec_r;
#pragma unroll 8
      for (int kq = 0; kq < 64; ++kq) {
        float4 wv = wd[(size_t)kq << 8];
        float4 h4 = *(const float4*)&h_lds[kq << 2];
        acc = fmaf(wv.x, h4.x, acc); acc = fmaf(wv.y, h4.y, acc);
        acc = fmaf(wv.z, h4.z, acc); acc = fmaf(wv.w, h4.w, acc);
      }
      dec_lds[tid] = acc * CE;
    }
    __syncthreads();
    // ---- P3: energy from LDS-resident attn: thread (chunk, tloc): te=tloc, 128 a ----
    {
      float eacc = 0.f;
      const unsigned short* arow = &attn_lds[tloc * 260 + chunk * 128];
#pragma unroll 8
      for (int q = 0; q < 32; ++q) {
        ushort4 ua = *(const ushort4*)&arow[q * 4];
        int ab = chunk * 128 + q * 4;
        float4 d = *(const float4*)&dec_lds[ab];
        float4 v = *(const float4*)&v2_lds[ab];
        eacc = fmaf(v.x, __builtin_amdgcn_rcpf(1.f + __builtin_amdgcn_exp2f(bf2f(ua.x) + d.x)), eacc);
        eacc = fmaf(v.y, __builtin_amdgcn_rcpf(1.f + __builtin_amdgcn_exp2f(bf2f(ua.y) + d.y)), eacc);
        eacc = fmaf(v.z, __builtin_amdgcn_rcpf(1.f + __builtin_amdgcn_exp2f(bf2f(ua.z) + d.z)), eacc);
        eacc = fmaf(v.w, __builtin_amdgcn_rcpf(1.f + __builtin_amdgcn_exp2f(bf2f(ua.w) + d.w)), eacc);
      }
      scratch[chunk * 128 + tloc] = eacc;
    }
    __syncthreads();
    // ---- P4: softmax numerator + slice denominator partial ----
    if (tid < 128) {
      float e = Sv_vb + scratch[tid] + scratch[128 + tid];
      float p = (maskv != 0.f) ? __builtin_amdgcn_exp2f(e * L2E) : 0.f;
      p_lds[tid] = p;
      for (int m = 32; m; m >>= 1) p += __shfl_xor(p, m);
      if (lane == 0) red_lds[w] = p;
    }
    __syncthreads();
    // ---- P5: ctx partials from pinned enc ----
    {
      float c0 = 0, c1 = 0, c2 = 0, c3 = 0;
#pragma unroll
      for (int i = 0; i < 32; ++i) {
        float pv = p_lds[w * 32 + i];
        float e0, e1, e2, e3;
        unpk(enc_r2[i].x, e0, e1);
        unpk(enc_r2[i].y, e2, e3);
        c0 = fmaf(pv, e0, c0); c1 = fmaf(pv, e1, c1);
        c2 = fmaf(pv, e2, c2); c3 = fmaf(pv, e3, c3);
      }
      float* cb = &ctxp_lds[w * 256 + lane * 4];
      cb[0] = c0; cb[1] = c1; cb[2] = c2; cb[3] = c3;
    }
    __syncthreads();
    {
      float cp = ctxp_lds[tid] + ctxp_lds[256 + tid] + ctxp_lds[512 + tid] + ctxp_lds[768 + tid];
      agstore(&ctxP[(size_t)(b * 8 + s) * 256 + tid], cp);
    }
    if (tid == 0) agstore(&sP[b * 8 + s], red_lds[0] + red_lds[1]);
    // ================= barrier 1 =================
    __threadfence();
    __syncthreads();
    if (tid == 0) {
      ++epoch;
      __hip_atomic_fetch_add(ctrb, 1u, __ATOMIC_RELEASE, __HIP_MEMORY_SCOPE_AGENT);
      while (__hip_atomic_load(ctrb, __ATOMIC_ACQUIRE, __HIP_MEMORY_SCOPE_AGENT) < 8u * epoch)
        __builtin_amdgcn_s_sleep(1);
    }
    __syncthreads();
    // ---- P6: assemble full ctx ----
    {
      if (tid < 8) red_lds[8 + tid] = agload(&sP[b * 8 + tid]);
      float csum = 0.f;
#pragma unroll
      for (int sp = 0; sp < 8; ++sp) csum += agload(&ctxP[(size_t)(b * 8 + sp) * 256 + tid]);
      __syncthreads();
      float S = red_lds[8] + red_lds[9] + red_lds[10] + red_lds[11] +
                red_lds[12] + red_lds[13] + red_lds[14] + red_lds[15];
      ctx_lds[tid] = csum * (1.f / S);
    }
    __syncthreads();
    // ---- P7: gate rows s*128..+128 (thread (chunk, tloc): half the kq each) ----
    {
      float gacc = 0.f;
      const int k0 = chunk * 32;
#pragma unroll 8
      for (int kq = k0; kq < k0 + 32; ++kq) {
        float4 wv = wpB[(size_t)kq << 10];
        float4 x = *(const float4*)&pre_lds[kq << 2];
        gacc = fmaf(wv.x, x.x, gacc); gacc = fmaf(wv.y, x.y, gacc);
        gacc = fmaf(wv.z, x.z, gacc); gacc = fmaf(wv.w, x.w, gacc);
      }
#pragma unroll 8
      for (int kq = k0; kq < k0 + 32; ++kq) {
        float4 wv = wcB[(size_t)kq << 10];
        float4 x = *(const float4*)&ctx_lds[kq << 2];
        gacc = fmaf(wv.x, x.x, gacc); gacc = fmaf(wv.y, x.y, gacc);
        gacc = fmaf(wv.z, x.z, gacc); gacc = fmaf(wv.w, x.w, gacc);
      }
#pragma unroll 8
      for (int kq = k0; kq < k0 + 32; ++kq) {
        float4 wv = whB[(size_t)kq << 10];
        float4 x = *(const float4*)&h_lds[kq << 2];
        gacc = fmaf(wv.x, x.x, gacc); gacc = fmaf(wv.y, x.y, gacc);
        gacc = fmaf(wv.z, x.z, gacc); gacc = fmaf(wv.w, x.w, gacc);
      }
      scratch[chunk * 128 + tloc] = gacc;
    }
    __syncthreads();
    if (tid < 128) {
      float g = biasg_r + scratch[tid] + scratch[128 + tid];
      agstore(&gP[(size_t)(b * 8 + s) * 128 + tid], g);
    }
    // ================= barrier 2 =================
    __threadfence();
    __syncthreads();
    if (tid == 0) {
      ++epoch;
      __hip_atomic_fetch_add(ctrb, 1u, __ATOMIC_RELEASE, __HIP_MEMORY_SCOPE_AGENT);
      while (__hip_atomic_load(ctrb, __ATOMIC_ACQUIRE, __HIP_MEMORY_SCOPE_AGENT) < 8u * epoch)
        __builtin_amdgcn_s_sleep(1);
    }
    __syncthreads();
    // ---- P8: LSTM pointwise (every WG computes full h', identical inputs) ----
    {
      const int hi = tid >> 7, lo = tid & 127;
      float ii = agload(&gP[(size_t)(b * 8 + 0 + hi) * 128 + lo]);
      float ff = agload(&gP[(size_t)(b * 8 + 2 + hi) * 128 + lo]);
      float gg = agload(&gP[(size_t)(b * 8 + 4 + hi) * 128 + lo]);
      float oo = agload(&gP[(size_t)(b * 8 + 6 + hi) * 128 + lo]);
      float si = __builtin_amdgcn_rcpf(1.f + __builtin_amdgcn_exp2f(-ii * L2E));
      float sf = __builtin_amdgcn_rcpf(1.f + __builtin_amdgcn_exp2f(-ff * L2E));
      float so = __builtin_amdgcn_rcpf(1.f + __builtin_amdgcn_exp2f(-oo * L2E));
      float tg2 = 1.f - 2.f * __builtin_amdgcn_rcpf(1.f + __builtin_amdgcn_exp2f(gg * CE));
      float cn = sf * c_reg + si * tg2;
      float tc = 1.f - 2.f * __builtin_amdgcn_rcpf(1.f + __builtin_amdgcn_exp2f(cn * CE));
      c_reg = cn;
      h_lds[tid] = so * tc;
    }
    __syncthreads();
    // ---- heads (only s==0 WG of each batch) ----
    if (s == 0) {
      if (tid < 160) {
        const int m = tid >> 1, q = tid & 1;
        float acc2 = melb_r;
        const float4* wm = (const float4*)(mel_W + (size_t)m * 512 + q * 256);
        const float4* xp = (q == 0) ? (const float4*)h_lds : (const float4*)ctx_lds;
#pragma unroll 8
        for (int i = 0; i < 64; ++i) {
          float4 wv = wm[i]; float4 x = xp[i];
          acc2 = fmaf(wv.x, x.x, acc2); acc2 = fmaf(wv.y, x.y, acc2);
          acc2 = fmaf(wv.z, x.z, acc2); acc2 = fmaf(wv.w, x.w, acc2);
        }
        acc2 += __shfl_xor(acc2, 1);
        if (q == 0) outm[it * 80 + m] = acc2;
      } else if (w == 3) {
        float acc2 = 0.f;
#pragma unroll
        for (int i = 0; i < 8; ++i) {
          int cc = lane * 8 + i;
          float x = (cc < 256) ? h_lds[cc] : ctx_lds[cc - 256];
          acc2 = fmaf(stopw[i], x, acc2);
        }
        for (int m = 32; m; m >>= 1) acc2 += __shfl_xor(acc2, m);
        if (lane == 0) outs[it] = acc2 + stopb0;
      }
    }
  }
}

extern "C" void kernel_launch(void* const* d_in, const int* in_sizes, int n_in,
                              void* d_out, int out_size, void* d_ws, size_t ws_size,
                              hipStream_t stream) {
  const float* enc = (const float*)d_in[0];
  const float* tmel = (const float*)d_in[1];
  const float* W_enc = (const float*)d_in[2];
  const float* b_enc = (const float*)d_in[3];
  const float* W_dec = (const float*)d_in[4];
  const float* b_dec = (const float*)d_in[5];
  const float* v_w = (const float*)d_in[6];
  const float* v_b = (const float*)d_in[7];
  const float* pW1 = (const float*)d_in[8];
  const float* pb1 = (const float*)d_in[9];
  const float* pW2 = (const float*)d_in[10];
  const float* pb2 = (const float*)d_in[11];
  const float* W_ih = (const float*)d_in[12];
  const float* W_hh = (const float*)d_in[13];
  const float* b_ih = (const float*)d_in[14];
  const float* b_hh = (const float*)d_in[15];
  const float* mel_W = (const float*)d_in[16];
  const float* mel_b = (const float*)d_in[17];
  const float* stop_W = (const float*)d_in[18];
  const float* stop_b = (const float*)d_in[19];
  const float* emask = (const float*)d_in[20];

  if (ws_size < WS_NEED) return;  // fail-visible rather than corrupt

  char* ws = (char*)d_ws;
  unsigned* attnT = (unsigned*)(ws + OFF_ATTNT);
  unsigned short* pre2 = (unsigned short*)(ws + OFF_PRE2);
  float* WdT = (float*)(ws + OFF_WDT);
  float* WhT = (float*)(ws + OFF_WHT);
  float* WcT = (float*)(ws + OFF_WCT);
  float* WpT = (float*)(ws + OFF_WPT);
  float* biasG = (float*)(ws + OFF_BIASG);
  float* exch = (float*)(ws + OFF_EXCH);
  unsigned* ctr = (unsigned*)(exch + EXF_CTR);

  hipMemsetAsync(exch, 0, EXCH_FLOATS * 4, stream);

  prep_w2<<<3332, 256, 0, stream>>>(W_dec, W_hh, W_ih, b_ih, b_hh, WdT, WhT, WcT, WpT, biasG);
  attn_gemm<<<1024, 256, 0, stream>>>(enc, W_enc, b_enc, attnT);
  prenet_fused<<<1000, 256, 0, stream>>>(tmel, pW1, pb1, pW2, pb2, pre2);
  decoder_split<<<512, 256, 0, stream>>>(
      attnT, enc, pre2, WdT, (const float4*)WhT, (const float4*)WcT, (const float4*)WpT,
      biasG, b_dec, v_w, v_b, emask, mel_W, mel_b, stop_W, stop_b,
      exch, ctr, (float*)d_out);
}